// Round 12
// baseline (309.051 us; speedup 1.0000x reference)
//
#include <hip/hip_runtime.h>
#include <math.h>

#define SEQ_LEN   720
#define IN_LEN    360
#define PRED_LEN  336
#define CHANNELS  862
#define RANK      32
#define BATCH     256

typedef _Float16 h2 __attribute__((ext_vector_type(2)));

// ws float offsets
#define WS_WP    0                   // Wp  [360][32] fp32
#define WS_VT    11520               // Vt  [336][32] fp32
#define WS_CVEC  22272               // cvec[336] fp32
#define WS_WH    22608               // packed W: u32[360*16] word[n*16+j] = (W[n][2j], W[n][2j+1])
#define WS_VH    28368               // packed V: u32[336*16] word[n*16+j] = (V[n][2j], V[n][2j+1])
#define WS_T     33744               // partial t: u32[2][256][862][16]  (h2-packed)
#define WS_S     7095248             // partial S: f32[2][256][862]
// total 7,536,592 floats = 30.1 MB (ws >= 58.3 MB proven in round 6)

__device__ __forceinline__ float fdot2w(h2 a, h2 b, float c) {
#if __has_builtin(__builtin_amdgcn_fdot2)
    return __builtin_amdgcn_fdot2(a, b, c, false);
#else
    return fmaf((float)a[0], (float)b[0], fmaf((float)a[1], (float)b[1], c));
#endif
}
__device__ __forceinline__ h2 pkrtz(float a, float b) {
    return __builtin_bit_cast(h2, __builtin_amdgcn_cvt_pkrtz(a, b));
}
#define BC(u)  __builtin_bit_cast(h2, (u))
#define BCU(v) __builtin_bit_cast(unsigned, (v))

// ---------------- prep: fold DCT/IDCT into Wp, Vt, cvec ----------------------
__global__ __launch_bounds__(256) void k_prep(const float* __restrict__ A,
                                              const float* __restrict__ B,
                                              const float* __restrict__ bias,
                                              float* __restrict__ Wp,
                                              float* __restrict__ Vt,
                                              float* __restrict__ cvec) {
    __shared__ float sbuf[IN_LEN * RANK];
    int blk = blockIdx.x;
    if (blk < 45) {
        for (int i = threadIdx.x; i < IN_LEN * RANK; i += 256) sbuf[i] = A[i];
        __syncthreads();
        int idx = blk * 256 + threadIdx.x;           // 45*256 == 11520
        int n = idx >> 5, r = idx & 31;
        int step = 2 * n + 1, m = 0;                 // k*(2n+1) mod 1440
        float sum = 0.f;
        for (int k = 0; k < IN_LEN; ++k) {
            float coef = (k == 0) ? 0.05270462766947299f    // 1/sqrt(360)
                                  : 0.07453559924999299f;   // 2/sqrt(720)
            float d = coef * cospif((float)m * (1.0f / 720.0f));
            sum = fmaf(d, sbuf[k * RANK + r], sum);
            m += step; if (m >= 1440) m -= 1440;
        }
        Wp[idx] = sum * 0.0019641855032960957f;      // (1/sqrt2)/360
    } else if (blk < 87) {
        for (int i = threadIdx.x; i < PRED_LEN * RANK; i += 256) {
            int r = i / PRED_LEN, k = i - r * PRED_LEN;
            sbuf[k * RANK + r] = B[i];               // B^T -> [k][r]
        }
        __syncthreads();
        int idx = (blk - 45) * 256 + threadIdx.x;    // 42*256 == 10752
        int n = idx >> 5, r = idx & 31;
        int step = 2 * n + 1, m = 0;                 // k*(2n+1) mod 1344
        float sum = 0.f;
        for (int k = 0; k < PRED_LEN; ++k) {
            float mk = cospif((float)m * (1.0f / 672.0f));
            if (k == 0) mk *= 0.5f;
            sum = fmaf(mk, sbuf[k * RANK + r], sum);
            m += step; if (m >= 1344) m -= 1344;
        }
        Vt[idx] = sum * (1.0f / 336.0f);
    } else {
        int n = (blk - 87) * 256 + threadIdx.x;
        if (n < PRED_LEN) {
            int step = 2 * n + 1, m = 0;
            float sum = 0.f;
            for (int k = 0; k < PRED_LEN; ++k) {
                float mk = cospif((float)m * (1.0f / 672.0f));
                if (k == 0) mk *= 0.5f;
                sum = fmaf(mk, bias[k], sum);
                m += step; if (m >= 1344) m -= 1344;
            }
            cvec[n] = sum * (1.0f / 336.0f);
        }
    }
}

// ---------------- pack fp32 weights into r-paired fp16 -----------------------
__global__ __launch_bounds__(256) void k_pack(const float* __restrict__ Wp,
                                              const float* __restrict__ Vt,
                                              unsigned* __restrict__ Wh,
                                              unsigned* __restrict__ Vh) {
    int idx = blockIdx.x * 256 + threadIdx.x;        // 44*256 = 11264 >= 11136
    if (idx < 5760) {                                // 360*16
        int n = idx >> 4, j = idx & 15;
        h2 v = pkrtz(Wp[n * RANK + 2 * j], Wp[n * RANK + 2 * j + 1]);
        Wh[idx] = BCU(v);
    } else if (idx < 5760 + 5376) {                  // 336*16
        int k = idx - 5760;
        int n = k >> 4, j = k & 15;
        h2 v = pkrtz(Vt[n * RANK + 2 * j], Vt[n * RANK + 2 * j + 1]);
        Vh[k] = BCU(v);
    }
}

// ---------------- kernel A: split-K partial t --------------------------------
// grid (2, BATCH): blockIdx.x = k-half. 512 thr, cpt=2 (431 active), fp16 h2
// accumulators (32 VGPR) -> ~90 VGPR total -> 2 blocks/CU x 8 waves = 16
// waves/CU (4/SIMD). W-half (11.5 KB) in LDS. Partials to ws (L3-resident).
__global__ __launch_bounds__(512) void k_part(const float* __restrict__ x,
                                              const unsigned* __restrict__ Wh,
                                              unsigned* __restrict__ wsT,
                                              float* __restrict__ wsS) {
    __shared__ uint4 lw4[720];                       // 180 n x 4 uint4 = 11520 B
    const int tid = threadIdx.x;
    const int kh = blockIdx.x;
    const int b  = blockIdx.y;

    for (int i = tid; i < 720; i += 512)
        lw4[i] = ((const uint4*)Wh)[kh * 720 + i];
    __syncthreads();

    const int c0 = 2 * tid;
    if (c0 >= CHANNELS) return;                      // no barriers after this

    h2 acc0[16], acc1[16];
    #pragma unroll
    for (int j = 0; j < 16; ++j) { acc0[j] = pkrtz(0.f, 0.f); acc1[j] = pkrtz(0.f, 0.f); }
    float S0 = 0.f, S1 = 0.f;

    const float* xp = x + (size_t)b * (SEQ_LEN * CHANNELS)
                        + (size_t)kh * (IN_LEN * CHANNELS) + c0;

    float2 bufA[8], bufB[8];
    #define LOADB(BUF, CH) { const float* p_ = xp + (size_t)(CH) * (8 * CHANNELS); \
        _Pragma("unroll") \
        for (int j_ = 0; j_ < 8; ++j_) BUF[j_] = *(const float2*)(p_ + j_ * CHANNELS); }

    // one n: rows e, o (float2 = ch c0, c0+1); W words at lw4[(NL)*4 .. +3]
    #define BODY1(E, O, NL) { \
        float p0 = E.x + O.x, p1 = E.y + O.y; \
        S0 += p0; S1 += p1; \
        h2 P0 = pkrtz(p0, p0), P1 = pkrtz(p1, p1); \
        const uint4* wr = lw4 + (NL) * 4; \
        _Pragma("unroll") \
        for (int q_ = 0; q_ < 4; ++q_) { \
            uint4 wv = wr[q_]; \
            h2 w0 = BC(wv.x), w1 = BC(wv.y), w2 = BC(wv.z), w3 = BC(wv.w); \
            acc0[4*q_+0] = w0 * P0 + acc0[4*q_+0]; \
            acc1[4*q_+0] = w0 * P1 + acc1[4*q_+0]; \
            acc0[4*q_+1] = w1 * P0 + acc0[4*q_+1]; \
            acc1[4*q_+1] = w1 * P1 + acc1[4*q_+1]; \
            acc0[4*q_+2] = w2 * P0 + acc0[4*q_+2]; \
            acc1[4*q_+2] = w2 * P1 + acc1[4*q_+2]; \
            acc0[4*q_+3] = w3 * P0 + acc0[4*q_+3]; \
            acc1[4*q_+3] = w3 * P1 + acc1[4*q_+3]; \
        } }

    // one 8-row chunk = 4 n
    #define BODY4(BUF, NB) { \
        BODY1(BUF[0], BUF[1], (NB) + 0) \
        BODY1(BUF[2], BUF[3], (NB) + 1) \
        BODY1(BUF[4], BUF[5], (NB) + 2) \
        BODY1(BUF[6], BUF[7], (NB) + 3) }

    LOADB(bufA, 0)
    for (int it = 0; it < 22; ++it) {                // chunks 0..43 + epilogue 44
        LOADB(bufB, 2 * it + 1)
        BODY4(bufA, 8 * it)
        LOADB(bufA, 2 * it + 2)                      // it=21 -> chunk 44 (valid)
        BODY4(bufB, 8 * it + 4)
    }
    BODY4(bufA, 176)                                 // chunk 44: n 176..179
    #undef BODY4
    #undef BODY1
    #undef LOADB

    // ---- store partial record: [kh][b][c][16] u32, 128 B/thread coalesced ----
    uint4* r4 = (uint4*)(wsT + ((size_t)(kh * BATCH + b) * CHANNELS + c0) * 16);
    #pragma unroll
    for (int q = 0; q < 4; ++q) {
        uint4 v;
        v.x = BCU(acc0[4*q+0]); v.y = BCU(acc0[4*q+1]);
        v.z = BCU(acc0[4*q+2]); v.w = BCU(acc0[4*q+3]);
        r4[q] = v;
        v.x = BCU(acc1[4*q+0]); v.y = BCU(acc1[4*q+1]);
        v.z = BCU(acc1[4*q+2]); v.w = BCU(acc1[4*q+3]);
        r4[4 + q] = v;
    }
    float2 sv; sv.x = S0; sv.y = S1;
    *(float2*)(wsS + (size_t)(kh * BATCH + b) * CHANNELS + c0) = sv;
}

// ---------------- kernel B: combine + finalize + phase 2 ---------------------
// grid (2, BATCH): blockIdx.x = n-half. 512 thr, cpt=2, 16 waves/CU.
// T reads are L3-hot (just written). V-half (10.75 KB) + cvec in LDS.
__global__ __launch_bounds__(512) void k_final(const float* __restrict__ A,
                                               const unsigned* __restrict__ Vh,
                                               const float* __restrict__ cvec,
                                               const unsigned* __restrict__ wsT,
                                               const float* __restrict__ wsS,
                                               float* __restrict__ out) {
    __shared__ uint4 lv4[672];                       // 168 n x 4 uint4 = 10752 B
    __shared__ float lcv[168];
    const int tid = threadIdx.x;
    const int nh = blockIdx.x;
    const int b  = blockIdx.y;

    for (int i = tid; i < 672; i += 512) lv4[i] = ((const uint4*)Vh)[nh * 672 + i];
    for (int i = tid; i < 168; i += 512) lcv[i] = cvec[nh * 168 + i];
    __syncthreads();

    const int c0 = 2 * tid;
    if (c0 >= CHANNELS) return;                      // no barriers after this

    // ---- combine k-halves (h2 adds) ----
    const uint4* rA = (const uint4*)(wsT + ((size_t)(0 * BATCH + b) * CHANNELS + c0) * 16);
    const uint4* rB = (const uint4*)(wsT + ((size_t)(1 * BATCH + b) * CHANNELS + c0) * 16);
    h2 t0[16], t1[16];
    #pragma unroll
    for (int q = 0; q < 4; ++q) {
        uint4 u = rA[q], v = rB[q];
        t0[4*q+0] = BC(u.x) + BC(v.x); t0[4*q+1] = BC(u.y) + BC(v.y);
        t0[4*q+2] = BC(u.z) + BC(v.z); t0[4*q+3] = BC(u.w) + BC(v.w);
        u = rA[4 + q]; v = rB[4 + q];
        t1[4*q+0] = BC(u.x) + BC(v.x); t1[4*q+1] = BC(u.y) + BC(v.y);
        t1[4*q+2] = BC(u.z) + BC(v.z); t1[4*q+3] = BC(u.w) + BC(v.w);
    }
    float2 sA = *(const float2*)(wsS + (size_t)(0 * BATCH + b) * CHANNELS + c0);
    float2 sB = *(const float2*)(wsS + (size_t)(1 * BATCH + b) * CHANNELS + c0);
    float S0 = sA.x + sB.x, S1 = sA.y + sB.y;

    // ---- finalize: t[r] -= S*(1/360)*A[0][r]/sqrt(720) ----
    const float kc = (1.0f / 360.0f) * 0.037267799624996496f;
    float g0 = -S0 * kc, g1 = -S1 * kc;
    h2 G0 = pkrtz(g0, g0), G1 = pkrtz(g1, g1);
    #pragma unroll
    for (int q = 0; q < 8; ++q) {
        float4 a4 = ((const float4*)A)[q];           // A[0][0..31], uniform, L2-hot
        h2 aa = pkrtz(a4.x, a4.y), ab = pkrtz(a4.z, a4.w);
        t0[2*q]   = aa * G0 + t0[2*q];   t0[2*q+1] = ab * G0 + t0[2*q+1];
        t1[2*q]   = aa * G1 + t1[2*q];   t1[2*q+1] = ab * G1 + t1[2*q+1];
    }
    const float mean0 = S0 * (1.0f / 720.0f);
    const float mean1 = S1 * (1.0f / 720.0f);

    // ---- phase 2: this half's 168 output rows ----
    float* op = out + (size_t)b * (PRED_LEN * CHANNELS)
                    + (size_t)(nh * 168) * CHANNELS + c0;
    #pragma unroll 2
    for (int nl = 0; nl < 168; ++nl) {
        const uint4* vr = lv4 + nl * 4;
        float oA0 = 0.f, oB0 = 0.f, oA1 = 0.f, oB1 = 0.f;
        #pragma unroll
        for (int q = 0; q < 4; ++q) {
            uint4 v = vr[q];
            oA0 = fdot2w(t0[4*q+0], BC(v.x), oA0);
            oA1 = fdot2w(t1[4*q+0], BC(v.x), oA1);
            oB0 = fdot2w(t0[4*q+1], BC(v.y), oB0);
            oB1 = fdot2w(t1[4*q+1], BC(v.y), oB1);
            oA0 = fdot2w(t0[4*q+2], BC(v.z), oA0);
            oA1 = fdot2w(t1[4*q+2], BC(v.z), oA1);
            oB0 = fdot2w(t0[4*q+3], BC(v.w), oB0);
            oB1 = fdot2w(t1[4*q+3], BC(v.w), oB1);
        }
        float cvn = lcv[nl];
        float2 o;
        o.x = (oA0 + oB0) + cvn + mean0;
        o.y = (oA1 + oB1) + cvn + mean1;
        *(float2*)op = o;
        op += CHANNELS;
    }
}

// ---------------- launcher ---------------------------------------------------

extern "C" void kernel_launch(void* const* d_in, const int* in_sizes, int n_in,
                              void* d_out, int out_size, void* d_ws, size_t ws_size,
                              hipStream_t stream) {
    (void)in_sizes; (void)n_in; (void)out_size; (void)ws_size;
    const float* x    = (const float*)d_in[0];
    const float* A    = (const float*)d_in[1];
    const float* B    = (const float*)d_in[2];
    const float* bias = (const float*)d_in[3];
    float* out = (float*)d_out;
    float* ws  = (float*)d_ws;

    float*    Wp   = ws + WS_WP;
    float*    Vt   = ws + WS_VT;
    float*    cvec = ws + WS_CVEC;
    unsigned* Wh   = (unsigned*)(ws + WS_WH);
    unsigned* Vh   = (unsigned*)(ws + WS_VH);
    unsigned* wsT  = (unsigned*)(ws + WS_T);
    float*    wsS  = ws + WS_S;

    k_prep<<<dim3(89), dim3(256), 0, stream>>>(A, B, bias, Wp, Vt, cvec);
    k_pack<<<dim3(44), dim3(256), 0, stream>>>(Wp, Vt, Wh, Vh);
    k_part<<<dim3(2, BATCH), dim3(512), 0, stream>>>(x, Wh, wsT, wsS);
    k_final<<<dim3(2, BATCH), dim3(512), 0, stream>>>(A, Vh, cvec, wsT, wsS, out);
}

// Round 13
// 249.043 us; speedup vs baseline: 1.2410x; 1.2410x over previous
//
#include <hip/hip_runtime.h>
#include <math.h>

#define SEQ_LEN   720
#define IN_LEN    360
#define PRED_LEN  336
#define CHANNELS  862
#define RANK      32
#define BATCH     256

typedef _Float16 h2 __attribute__((ext_vector_type(2)));

// ws u32/f32 offsets (packed weights only; fp32 staging eliminated)
#define WS_WH    0        // packed W: u32[360*16]  word[n*16+j] = (W[n][2j], W[n][2j+1])
#define WS_VH    5760     // packed V: u32[336*16]  word[n*16+j] = (V[n][2j], V[n][2j+1])
#define WS_CV    11136    // cvec[336] fp32

// LDS u32 offsets (total 40848 u32 = 163392 B <= 163840; proven OK in R10)
#define L_EX     0        // [432 slots][68 u32]  (acc h2[4][16] + S[4])
#define L_W      29376    // u32[5760]
#define L_V      35136    // u32[5376]
#define L_CV     40512    // f32[336]

__device__ __forceinline__ float fdot2w(h2 a, h2 b, float c) {
#if __has_builtin(__builtin_amdgcn_fdot2)
    return __builtin_amdgcn_fdot2(a, b, c, false);
#else
    return fmaf((float)a[0], (float)b[0], fmaf((float)a[1], (float)b[1], c));
#endif
}
__device__ __forceinline__ h2 pkrtz(float a, float b) {
    return __builtin_bit_cast(h2, __builtin_amdgcn_cvt_pkrtz(a, b));
}
#define BC(u)  __builtin_bit_cast(h2, (u))
#define BCU(v) __builtin_bit_cast(unsigned, (v))

__device__ __forceinline__ void ntstore2(float* p, float2 v) {
    __builtin_nontemporal_store(__builtin_bit_cast(unsigned long long, v),
                                (unsigned long long*)p);
}

// ---------------- fused prep: fold DCT/IDCT and pack fp16 in one pass --------
// blocks 0-44: W rows (8 n x 32 r per block) -> Wh r-paired fp16
// blocks 45-86: V rows -> Vh r-paired fp16;  blocks 87-88: cvec fp32
__global__ __launch_bounds__(256) void k_prep(const float* __restrict__ A,
                                              const float* __restrict__ B,
                                              const float* __restrict__ bias,
                                              unsigned* __restrict__ Wh,
                                              unsigned* __restrict__ Vh,
                                              float* __restrict__ cvec) {
    __shared__ float sbuf[IN_LEN * RANK];            // 46080 B
    __shared__ float sres[256];
    const int t = threadIdx.x;
    int blk = blockIdx.x;
    if (blk < 45) {
        for (int i = t; i < IN_LEN * RANK; i += 256) sbuf[i] = A[i];
        __syncthreads();
        int n = blk * 8 + (t >> 5), r = t & 31;
        int step = 2 * n + 1, m = 0;                 // k*(2n+1) mod 1440
        float sum = 0.f;
        for (int k = 0; k < IN_LEN; ++k) {
            float coef = (k == 0) ? 0.05270462766947299f    // 1/sqrt(360)
                                  : 0.07453559924999299f;   // 2/sqrt(720)
            float d = coef * cospif((float)m * (1.0f / 720.0f));
            sum = fmaf(d, sbuf[k * RANK + r], sum);
            m += step; if (m >= 1440) m -= 1440;
        }
        sres[t] = sum * 0.0019641855032960957f;      // (1/sqrt2)/360
        __syncthreads();
        if (t < 128) {
            int nl = t >> 4, j = t & 15;
            h2 v = pkrtz(sres[nl * 32 + 2 * j], sres[nl * 32 + 2 * j + 1]);
            Wh[(blk * 8 + nl) * 16 + j] = BCU(v);
        }
    } else if (blk < 87) {
        for (int i = t; i < PRED_LEN * RANK; i += 256) {
            int r = i / PRED_LEN, k = i - r * PRED_LEN;
            sbuf[k * RANK + r] = B[i];               // B^T -> [k][r]
        }
        __syncthreads();
        int n = (blk - 45) * 8 + (t >> 5), r = t & 31;
        int step = 2 * n + 1, m = 0;                 // k*(2n+1) mod 1344
        float sum = 0.f;
        for (int k = 0; k < PRED_LEN; ++k) {
            float mk = cospif((float)m * (1.0f / 672.0f));
            if (k == 0) mk *= 0.5f;
            sum = fmaf(mk, sbuf[k * RANK + r], sum);
            m += step; if (m >= 1344) m -= 1344;
        }
        sres[t] = sum * (1.0f / 336.0f);
        __syncthreads();
        if (t < 128) {
            int nl = t >> 4, j = t & 15;
            h2 v = pkrtz(sres[nl * 32 + 2 * j], sres[nl * 32 + 2 * j + 1]);
            Vh[((blk - 45) * 8 + nl) * 16 + j] = BCU(v);
        }
    } else {
        int n = (blk - 87) * 256 + t;
        if (n < PRED_LEN) {
            int step = 2 * n + 1, m = 0;
            float sum = 0.f;
            for (int k = 0; k < PRED_LEN; ++k) {
                float mk = cospif((float)m * (1.0f / 672.0f));
                if (k == 0) mk *= 0.5f;
                sum = fmaf(mk, bias[k], sum);
                m += step; if (m >= 1344) m -= 1344;
            }
            cvec[n] = sum * (1.0f / 336.0f);
        }
    }
}

// ---------------- fused main kernel (R10 + deep prefetch + nt stores) --------
// One 512-thr block per batch (grid 256 -> 1 block/CU, 8 waves/CU).
// tid>>8 = K-half; i=tid&255, i<216 active, 4 ch/thread, full-row sweeps.
// 4-buffer x pipeline (~3 LOADNs in flight = ~27 KB/CU outstanding).
// fp16 packed accumulators; partials exchanged via LDS; phase 2 n-split.
__global__ __launch_bounds__(512) void k_main(const float* __restrict__ x,
                                              const float* __restrict__ A,
                                              const unsigned* __restrict__ Wh,
                                              const unsigned* __restrict__ Vh,
                                              const float* __restrict__ cvec,
                                              float* __restrict__ out) {
    __shared__ unsigned ldsu[40848];                 // 163392 B
    const int tid = threadIdx.x;
    const int b = blockIdx.x;
    const int h = tid >> 8;
    const int i = tid & 255;
    const bool active = (i < 216);
    const int c0 = (i < 215) ? 4 * i : 858;          // last thread overlaps by 2 (dup writes)

    // ---- stage W, V, cvec ----
    for (int idx = tid; idx < 1440; idx += 512)
        ((uint4*)(ldsu + L_W))[idx] = ((const uint4*)Wh)[idx];
    for (int idx = tid; idx < 1344; idx += 512)
        ((uint4*)(ldsu + L_V))[idx] = ((const uint4*)Vh)[idx];
    for (int idx = tid; idx < 84; idx += 512)
        ((uint4*)(ldsu + L_CV))[idx] = ((const uint4*)cvec)[idx];
    __syncthreads();

    h2 acc0[16], acc1[16], acc2[16], acc3[16];
    #pragma unroll
    for (int j = 0; j < 16; ++j) {
        acc0[j] = pkrtz(0.f, 0.f); acc1[j] = pkrtz(0.f, 0.f);
        acc2[j] = pkrtz(0.f, 0.f); acc3[j] = pkrtz(0.f, 0.f);
    }
    float S0 = 0.f, S1 = 0.f, S2 = 0.f, S3 = 0.f;

    // ---- phase 1: partial t over this half's 180 n (360 rows) ----
    if (active) {
        const float* xp = x + (size_t)b * (SEQ_LEN * CHANNELS)
                            + (size_t)h * (IN_LEN * CHANNELS) + c0;
        float2 b0[4], b1[4], b2[4], b3[4];
        #define LOADN(BUF, NL) { const float* p_ = xp + (size_t)(2 * (NL)) * CHANNELS; \
            BUF[0] = *(const float2*)(p_);                 \
            BUF[1] = *(const float2*)(p_ + 2);             \
            BUF[2] = *(const float2*)(p_ + CHANNELS);      \
            BUF[3] = *(const float2*)(p_ + CHANNELS + 2); }

        #define BODY(BUF, NL) { \
            float p0 = BUF[0].x + BUF[2].x; \
            float p1 = BUF[0].y + BUF[2].y; \
            float p2 = BUF[1].x + BUF[3].x; \
            float p3 = BUF[1].y + BUF[3].y; \
            S0 += p0; S1 += p1; S2 += p2; S3 += p3; \
            h2 P0 = pkrtz(p0, p0), P1 = pkrtz(p1, p1); \
            h2 P2 = pkrtz(p2, p2), P3 = pkrtz(p3, p3); \
            const uint4* wr = (const uint4*)(ldsu + L_W) + ((NL) + 180 * h) * 4; \
            _Pragma("unroll") \
            for (int q_ = 0; q_ < 4; ++q_) { \
                uint4 wv = wr[q_]; \
                h2 w0 = BC(wv.x), w1 = BC(wv.y), w2 = BC(wv.z), w3 = BC(wv.w); \
                acc0[4*q_+0] = w0 * P0 + acc0[4*q_+0]; \
                acc1[4*q_+0] = w0 * P1 + acc1[4*q_+0]; \
                acc2[4*q_+0] = w0 * P2 + acc2[4*q_+0]; \
                acc3[4*q_+0] = w0 * P3 + acc3[4*q_+0]; \
                acc0[4*q_+1] = w1 * P0 + acc0[4*q_+1]; \
                acc1[4*q_+1] = w1 * P1 + acc1[4*q_+1]; \
                acc2[4*q_+1] = w1 * P2 + acc2[4*q_+1]; \
                acc3[4*q_+1] = w1 * P3 + acc3[4*q_+1]; \
                acc0[4*q_+2] = w2 * P0 + acc0[4*q_+2]; \
                acc1[4*q_+2] = w2 * P1 + acc1[4*q_+2]; \
                acc2[4*q_+2] = w2 * P2 + acc2[4*q_+2]; \
                acc3[4*q_+2] = w2 * P3 + acc3[4*q_+2]; \
                acc0[4*q_+3] = w3 * P0 + acc0[4*q_+3]; \
                acc1[4*q_+3] = w3 * P1 + acc1[4*q_+3]; \
                acc2[4*q_+3] = w3 * P2 + acc2[4*q_+3]; \
                acc3[4*q_+3] = w3 * P3 + acc3[4*q_+3]; \
            } }

        LOADN(b0, 0) LOADN(b1, 1) LOADN(b2, 2)
        for (int it = 0; it < 45; ++it) {            // n = 4it .. 4it+3
            const int base = 4 * it;
            LOADN(b3, base + 3)
            BODY(b0, base)
            { int nn = (base + 4 < 180) ? base + 4 : 179; LOADN(b0, nn) }
            BODY(b1, base + 1)
            { int nn = (base + 5 < 180) ? base + 5 : 179; LOADN(b1, nn) }
            BODY(b2, base + 2)
            { int nn = (base + 6 < 180) ? base + 6 : 179; LOADN(b2, nn) }
            BODY(b3, base + 3)
        }
        #undef BODY
        #undef LOADN
    }

    // ---- write partial record (16B-aligned: 272 B/slot) ----
    if (active) {
        uint4* rec = (uint4*)(ldsu + (i + 216 * h) * 68);
        #pragma unroll
        for (int q = 0; q < 4; ++q) {
            uint4 v;
            v.x = BCU(acc0[4*q+0]); v.y = BCU(acc0[4*q+1]);
            v.z = BCU(acc0[4*q+2]); v.w = BCU(acc0[4*q+3]);
            rec[q] = v;
            v.x = BCU(acc1[4*q+0]); v.y = BCU(acc1[4*q+1]);
            v.z = BCU(acc1[4*q+2]); v.w = BCU(acc1[4*q+3]);
            rec[4 + q] = v;
            v.x = BCU(acc2[4*q+0]); v.y = BCU(acc2[4*q+1]);
            v.z = BCU(acc2[4*q+2]); v.w = BCU(acc2[4*q+3]);
            rec[8 + q] = v;
            v.x = BCU(acc3[4*q+0]); v.y = BCU(acc3[4*q+1]);
            v.z = BCU(acc3[4*q+2]); v.w = BCU(acc3[4*q+3]);
            rec[12 + q] = v;
        }
        uint4 sv;
        sv.x = __float_as_uint(S0); sv.y = __float_as_uint(S1);
        sv.z = __float_as_uint(S2); sv.w = __float_as_uint(S3);
        rec[16] = sv;
    }
    __syncthreads();

    if (active) {
        // ---- combine partner half ----
        const uint4* pr = (const uint4*)(ldsu + (i + 216 * (1 - h)) * 68);
        #pragma unroll
        for (int q = 0; q < 4; ++q) {
            uint4 v = pr[q];
            acc0[4*q+0] = acc0[4*q+0] + BC(v.x); acc0[4*q+1] = acc0[4*q+1] + BC(v.y);
            acc0[4*q+2] = acc0[4*q+2] + BC(v.z); acc0[4*q+3] = acc0[4*q+3] + BC(v.w);
            v = pr[4 + q];
            acc1[4*q+0] = acc1[4*q+0] + BC(v.x); acc1[4*q+1] = acc1[4*q+1] + BC(v.y);
            acc1[4*q+2] = acc1[4*q+2] + BC(v.z); acc1[4*q+3] = acc1[4*q+3] + BC(v.w);
            v = pr[8 + q];
            acc2[4*q+0] = acc2[4*q+0] + BC(v.x); acc2[4*q+1] = acc2[4*q+1] + BC(v.y);
            acc2[4*q+2] = acc2[4*q+2] + BC(v.z); acc2[4*q+3] = acc2[4*q+3] + BC(v.w);
            v = pr[12 + q];
            acc3[4*q+0] = acc3[4*q+0] + BC(v.x); acc3[4*q+1] = acc3[4*q+1] + BC(v.y);
            acc3[4*q+2] = acc3[4*q+2] + BC(v.z); acc3[4*q+3] = acc3[4*q+3] + BC(v.w);
        }
        uint4 sv = pr[16];
        float S0f = S0 + __uint_as_float(sv.x), S1f = S1 + __uint_as_float(sv.y);
        float S2f = S2 + __uint_as_float(sv.z), S3f = S3 + __uint_as_float(sv.w);

        // ---- finalize: t[r] -= S*(1/360)*A[0][r]/sqrt(720) ----
        const float kc = (1.0f / 360.0f) * 0.037267799624996496f;
        float g0 = -S0f * kc, g1 = -S1f * kc, g2 = -S2f * kc, g3 = -S3f * kc;
        h2 G0 = pkrtz(g0, g0), G1 = pkrtz(g1, g1), G2 = pkrtz(g2, g2), G3 = pkrtz(g3, g3);
        #pragma unroll
        for (int q = 0; q < 8; ++q) {
            float4 a4 = ((const float4*)A)[q];       // A[0][0..31], uniform, L2-hot
            h2 aa = pkrtz(a4.x, a4.y), ab = pkrtz(a4.z, a4.w);
            acc0[2*q]   = aa * G0 + acc0[2*q];   acc0[2*q+1] = ab * G0 + acc0[2*q+1];
            acc1[2*q]   = aa * G1 + acc1[2*q];   acc1[2*q+1] = ab * G1 + acc1[2*q+1];
            acc2[2*q]   = aa * G2 + acc2[2*q];   acc2[2*q+1] = ab * G2 + acc2[2*q+1];
            acc3[2*q]   = aa * G3 + acc3[2*q];   acc3[2*q+1] = ab * G3 + acc3[2*q+1];
        }
        const float mean0 = S0f * (1.0f / 720.0f), mean1 = S1f * (1.0f / 720.0f);
        const float mean2 = S2f * (1.0f / 720.0f), mean3 = S3f * (1.0f / 720.0f);

        // ---- phase 2: this half's 168 output rows (nontemporal stores) ----
        float* op = out + (size_t)b * (PRED_LEN * CHANNELS)
                        + (size_t)(168 * h) * CHANNELS + c0;
        for (int nl = 0; nl < 168; ++nl) {
            const int n = 168 * h + nl;
            const uint4* vr = (const uint4*)(ldsu + L_V) + n * 4;
            float o0 = 0.f, o1 = 0.f, o2 = 0.f, o3 = 0.f;
            float e0 = 0.f, e1 = 0.f, e2 = 0.f, e3 = 0.f;
            #pragma unroll
            for (int q = 0; q < 4; ++q) {
                uint4 v = vr[q];
                h2 v0 = BC(v.x), v1 = BC(v.y), v2 = BC(v.z), v3 = BC(v.w);
                o0 = fdot2w(acc0[4*q+0], v0, o0); e0 = fdot2w(acc0[4*q+1], v1, e0);
                o1 = fdot2w(acc1[4*q+0], v0, o1); e1 = fdot2w(acc1[4*q+1], v1, e1);
                o2 = fdot2w(acc2[4*q+0], v0, o2); e2 = fdot2w(acc2[4*q+1], v1, e2);
                o3 = fdot2w(acc3[4*q+0], v0, o3); e3 = fdot2w(acc3[4*q+1], v1, e3);
                o0 = fdot2w(acc0[4*q+2], v2, o0); e0 = fdot2w(acc0[4*q+3], v3, e0);
                o1 = fdot2w(acc1[4*q+2], v2, o1); e1 = fdot2w(acc1[4*q+3], v3, e1);
                o2 = fdot2w(acc2[4*q+2], v2, o2); e2 = fdot2w(acc2[4*q+3], v3, e2);
                o3 = fdot2w(acc3[4*q+2], v2, o3); e3 = fdot2w(acc3[4*q+3], v3, e3);
            }
            float cvn = ((const float*)(ldsu + L_CV))[n];
            float2 w0, w1;
            w0.x = (o0 + e0) + cvn + mean0;
            w0.y = (o1 + e1) + cvn + mean1;
            w1.x = (o2 + e2) + cvn + mean2;
            w1.y = (o3 + e3) + cvn + mean3;
            ntstore2(op,     w0);
            ntstore2(op + 2, w1);
            op += CHANNELS;
        }
    }
}

// ---------------- launcher ---------------------------------------------------

extern "C" void kernel_launch(void* const* d_in, const int* in_sizes, int n_in,
                              void* d_out, int out_size, void* d_ws, size_t ws_size,
                              hipStream_t stream) {
    (void)in_sizes; (void)n_in; (void)out_size; (void)ws_size;
    const float* x    = (const float*)d_in[0];
    const float* A    = (const float*)d_in[1];
    const float* B    = (const float*)d_in[2];
    const float* bias = (const float*)d_in[3];
    float* out = (float*)d_out;

    unsigned* Wh   = (unsigned*)d_ws + WS_WH;
    unsigned* Vh   = (unsigned*)d_ws + WS_VH;
    float*    cvec = (float*)d_ws + WS_CV;

    k_prep<<<dim3(89), dim3(256), 0, stream>>>(A, B, bias, Wh, Vh, cvec);
    k_main<<<dim3(BATCH), dim3(512), 0, stream>>>(x, A, Wh, Vh, cvec, out);
}